// Round 6
// baseline (1032.247 us; speedup 1.0000x reference)
//
#include <hip/hip_runtime.h>

#define N_NODES 50000
#define N_GRAPHS 500
#define E_SPARSE 800000
#define E_DENSE 3200000
#define IN_DIM 128
#define HID 128
#define OUT_D 64
#define N_LAYERS 3
#define NEG_SLOPE 0.2f

#define BUCKET_SHIFT 7                 // 128 nodes per bucket
#define BUCKET_N 128
#define NBUCK 391                      // ceil(50000/128)
#define NTILE 256                      // edge tiles
typedef unsigned int u32;
typedef unsigned short u16;

// ---------------- CSR construction (no global atomics) ---------------------

__global__ __launch_bounds__(256) void tile_count(const int* __restrict__ dst, int E,
                                                  int TS, int* __restrict__ mat) {
    __shared__ int hc[NBUCK];
    int t = threadIdx.x, tile = blockIdx.x;
    for (int i = t; i < NBUCK; i += 256) hc[i] = 0;
    __syncthreads();
    int beg = tile * TS, end = min(E, beg + TS);
    for (int i = beg + t; i < end; i += 256) atomicAdd(&hc[dst[i] >> BUCKET_SHIFT], 1);
    __syncthreads();
    for (int i = t; i < NBUCK; i += 256) mat[i * NTILE + tile] = hc[i];
}

__global__ void scan_lvl0(const int* __restrict__ cnt, int n,
                          int* __restrict__ out, int* __restrict__ bsum) {
    __shared__ int sm[512];
    int t = threadIdx.x;
    int base = blockIdx.x * 2048 + t * 4;
    int v0 = (base + 0 < n) ? cnt[base + 0] : 0;
    int v1 = (base + 1 < n) ? cnt[base + 1] : 0;
    int v2 = (base + 2 < n) ? cnt[base + 2] : 0;
    int v3 = (base + 3 < n) ? cnt[base + 3] : 0;
    int s = v0 + v1 + v2 + v3;
    sm[t] = s;
    __syncthreads();
    for (int off = 1; off < 512; off <<= 1) {
        int a = (t >= off) ? sm[t - off] : 0;
        __syncthreads();
        sm[t] += a;
        __syncthreads();
    }
    int excl = sm[t] - s;
    if (base + 0 < n) out[base + 0] = excl;
    if (base + 1 < n) out[base + 1] = excl + v0;
    if (base + 2 < n) out[base + 2] = excl + v0 + v1;
    if (base + 3 < n) out[base + 3] = excl + v0 + v1 + v2;
    if (t == 511) bsum[blockIdx.x] = sm[511];
}

__global__ void scan_lvl1(int* __restrict__ bsum, int nb, int* __restrict__ bsumx) {
    int t = threadIdx.x;
    int v = (t < nb) ? bsum[t] : 0;
    int orig = v;
    for (int off = 1; off < 64; off <<= 1) {
        int u = __shfl_up(v, off);
        if (t >= off) v += u;
    }
    if (t < nb) bsumx[t] = v - orig;
}

__global__ void scan_add(int* __restrict__ out, int n, const int* __restrict__ bsumx,
                         int Etot) {
    int i = blockIdx.x * blockDim.x + threadIdx.x;
    if (i < n) out[i] += bsumx[i >> 11];
    if (i == 0) out[n] = Etot;
}

// Pass A3: scatter packed (dst_low7<<16 | src) into (bucket,tile) runs.
__global__ __launch_bounds__(256) void tile_scatter(const int* __restrict__ src,
                                                    const int* __restrict__ dst, int E,
                                                    int TS, const int* __restrict__ matx,
                                                    u32* __restrict__ pairs) {
    __shared__ int cur[NBUCK];
    int t = threadIdx.x, tile = blockIdx.x;
    for (int i = t; i < NBUCK; i += 256) cur[i] = matx[i * NTILE + tile];
    __syncthreads();
    int beg = tile * TS, end = min(E, beg + TS);
    for (int i = beg + t; i < end; i += 256) {
        int d = dst[i];
        int pos = atomicAdd(&cur[d >> BUCKET_SHIFT], 1);
        pairs[pos] = (u32)src[i] | ((u32)(d & (BUCKET_N - 1)) << 16);
    }
}

// Pass B: per-bucket local sort. Builds rowptr (LDS hist+scan) and u16 csrc.
__global__ __launch_bounds__(256) void bucket_to_csr(const u32* __restrict__ pairs,
                                                     const int* __restrict__ matx, int E,
                                                     int* __restrict__ rowptr,
                                                     u16* __restrict__ csrc) {
    int b = blockIdx.x;
    int t = threadIdx.x;
    int beg = matx[b * NTILE];
    int end = matx[(b + 1) * NTILE];
    __shared__ int lcnt[BUCKET_N];
    __shared__ int lofs[BUCKET_N];
    if (t < BUCKET_N) lcnt[t] = 0;
    __syncthreads();
    for (int k = beg + t; k < end; k += 256)
        atomicAdd(&lcnt[(pairs[k] >> 16) & (BUCKET_N - 1)], 1);
    __syncthreads();
    if (t < BUCKET_N) lofs[t] = lcnt[t];
    __syncthreads();
    for (int off = 1; off < BUCKET_N; off <<= 1) {
        int a = (t < BUCKET_N && t >= off) ? lofs[t - off] : 0;
        __syncthreads();
        if (t < BUCKET_N) lofs[t] += a;
        __syncthreads();
    }
    int node = (b << BUCKET_SHIFT) + t;
    if (t < BUCKET_N) {
        int excl = lofs[t] - lcnt[t];
        if (node < N_NODES) rowptr[node] = beg + excl;
        lcnt[t] = excl;  // reuse as cursor
    }
    if (b == NBUCK - 1 && t == 0) rowptr[N_NODES] = E;
    __syncthreads();
    for (int k = beg + t; k < end; k += 256) {
        u32 pr = pairs[k];
        int dl = (pr >> 16) & (BUCKET_N - 1);
        int pos = atomicAdd(&lcnt[dl], 1);
        csrc[beg + pos] = (u16)(pr & 0xffffu);
    }
}

// ---------------- per-layer kernels ----------------------------------------

// One wave per node: h[node][j] = dot(x[node,:], W[:,j]); wave-reduce scores.
__global__ void node_mm(const float* __restrict__ x, const float* __restrict__ W,
                        const float* __restrict__ a_s, const float* __restrict__ a_d,
                        float* __restrict__ h, float* __restrict__ s_src,
                        float* __restrict__ s_dst) {
    int node = blockIdx.x;
    int j = threadIdx.x;  // 0..63
    __shared__ float xs[IN_DIM];
    const float* xr = x + (size_t)node * IN_DIM;
    xs[j] = xr[j];
    xs[j + 64] = xr[j + 64];
    __syncthreads();
    float acc = 0.f;
#pragma unroll 8
    for (int k = 0; k < IN_DIM; ++k) acc += xs[k] * W[k * OUT_D + j];
    h[(size_t)node * OUT_D + j] = acc;
    float ps = acc * a_s[j];
    float pd = acc * a_d[j];
    for (int off = 32; off > 0; off >>= 1) {
        ps += __shfl_down(ps, off);
        pd += __shfl_down(pd, off);
    }
    if (j == 0) { s_src[node] = ps; s_dst[node] = pd; }
}

// Sparse-branch fused GAT aggregation (R5 structure, u16 csrc).
__global__ __launch_bounds__(256) void gat_aggr(
    const int* __restrict__ rowptr, const u16* __restrict__ csrc,
    const float* __restrict__ s_src, const float* __restrict__ s_dst,
    const float* __restrict__ h, const float* __restrict__ bias,
    float* __restrict__ xnext, int col_off) {
    int node = blockIdx.x * 4 + (threadIdx.x >> 6);
    if (node >= N_NODES) return;
    int lane = threadIdx.x & 63;
    int grp = lane >> 3;   // 0..7
    int sub = lane & 7;    // 0..7

    int beg = rowptr[node];
    int end = rowptr[node + 1];
    float sd = s_dst[node];

    const float4* h4 = (const float4*)h;
    float4 a0 = make_float4(0.f, 0.f, 0.f, 0.f);
    float4 a1 = make_float4(0.f, 0.f, 0.f, 0.f);
    float z = 0.f;

    int k = beg + grp;
    for (; k + 8 < end; k += 16) {
        int s0 = csrc[k];
        int s1 = csrc[k + 8];
        float e0 = s_src[s0] + sd;
        float e1 = s_src[s1] + sd;
        e0 = (e0 >= 0.f) ? e0 : NEG_SLOPE * e0;
        e1 = (e1 >= 0.f) ? e1 : NEG_SLOPE * e1;
        float p0 = __expf(e0);
        float p1 = __expf(e1);
        float4 u0 = h4[(size_t)s0 * 16 + sub];
        float4 u1 = h4[(size_t)s0 * 16 + sub + 8];
        float4 v0 = h4[(size_t)s1 * 16 + sub];
        float4 v1 = h4[(size_t)s1 * 16 + sub + 8];
        z += p0 + p1;
        a0.x += p0 * u0.x + p1 * v0.x; a0.y += p0 * u0.y + p1 * v0.y;
        a0.z += p0 * u0.z + p1 * v0.z; a0.w += p0 * u0.w + p1 * v0.w;
        a1.x += p0 * u1.x + p1 * v1.x; a1.y += p0 * u1.y + p1 * v1.y;
        a1.z += p0 * u1.z + p1 * v1.z; a1.w += p0 * u1.w + p1 * v1.w;
    }
    if (k < end) {
        int s0 = csrc[k];
        float e0 = s_src[s0] + sd;
        e0 = (e0 >= 0.f) ? e0 : NEG_SLOPE * e0;
        float p0 = __expf(e0);
        float4 u0 = h4[(size_t)s0 * 16 + sub];
        float4 u1 = h4[(size_t)s0 * 16 + sub + 8];
        z += p0;
        a0.x += p0 * u0.x; a0.y += p0 * u0.y; a0.z += p0 * u0.z; a0.w += p0 * u0.w;
        a1.x += p0 * u1.x; a1.y += p0 * u1.y; a1.z += p0 * u1.z; a1.w += p0 * u1.w;
    }
    if (grp == 0) {
        float e0 = s_src[node] + sd;
        e0 = (e0 >= 0.f) ? e0 : NEG_SLOPE * e0;
        float p0 = __expf(e0);
        float4 u0 = h4[(size_t)node * 16 + sub];
        float4 u1 = h4[(size_t)node * 16 + sub + 8];
        z += p0;
        a0.x += p0 * u0.x; a0.y += p0 * u0.y; a0.z += p0 * u0.z; a0.w += p0 * u0.w;
        a1.x += p0 * u1.x; a1.y += p0 * u1.y; a1.z += p0 * u1.z; a1.w += p0 * u1.w;
    }
#pragma unroll
    for (int off = 8; off <= 32; off <<= 1) {
        a0.x += __shfl_xor(a0.x, off); a0.y += __shfl_xor(a0.y, off);
        a0.z += __shfl_xor(a0.z, off); a0.w += __shfl_xor(a0.w, off);
        a1.x += __shfl_xor(a1.x, off); a1.y += __shfl_xor(a1.y, off);
        a1.z += __shfl_xor(a1.z, off); a1.w += __shfl_xor(a1.w, off);
        z += __shfl_xor(z, off);
    }
    if (grp == 0) {
        float inv = 1.f / z;
        const float4* b4 = (const float4*)bias;
        float4 b0 = b4[sub], b1 = b4[sub + 8];
        float4 o0, o1;
        o0.x = a0.x * inv + b0.x; o0.y = a0.y * inv + b0.y;
        o0.z = a0.z * inv + b0.z; o0.w = a0.w * inv + b0.w;
        o1.x = a1.x * inv + b1.x; o1.y = a1.y * inv + b1.y;
        o1.z = a1.z * inv + b1.z; o1.w = a1.w * inv + b1.w;
        o0.x = fmaxf(o0.x, 0.f); o0.y = fmaxf(o0.y, 0.f);
        o0.z = fmaxf(o0.z, 0.f); o0.w = fmaxf(o0.w, 0.f);
        o1.x = fmaxf(o1.x, 0.f); o1.y = fmaxf(o1.y, 0.f);
        o1.z = fmaxf(o1.z, 0.f); o1.w = fmaxf(o1.w, 0.f);
        float4* outp = (float4*)(xnext + (size_t)node * HID + col_off);
        outp[sub] = o0;
        outp[sub + 8] = o1;
    }
}

// Dense-branch pass 1: z[node] = sum(exp(leaky(score))) incl. self-loop.
__global__ __launch_bounds__(256) void gat_z(
    const int* __restrict__ rowptr, const u16* __restrict__ csrc,
    const float* __restrict__ s_src, const float* __restrict__ s_dst,
    float* __restrict__ zbuf) {
    int node = blockIdx.x * 4 + (threadIdx.x >> 6);
    if (node >= N_NODES) return;
    int lane = threadIdx.x & 63;
    int beg = rowptr[node], end = rowptr[node + 1];
    float sd = s_dst[node];
    float z = 0.f;
    for (int k = beg + lane; k < end; k += 64) {
        float e = s_src[csrc[k]] + sd;
        e = (e >= 0.f) ? e : NEG_SLOPE * e;
        z += __expf(e);
    }
    if (lane == 0) {
        float e0 = s_src[node] + sd;
        e0 = (e0 >= 0.f) ? e0 : NEG_SLOPE * e0;
        z += __expf(e0);
    }
#pragma unroll
    for (int off = 1; off < 64; off <<= 1) z += __shfl_xor(z, off);
    if (lane == 0) zbuf[node] = z;
}

// Dense-branch pass 2 (one dispatch per 16-dim slice; h slice = 3.2MB, fits
// per-XCD L2 so gathers become L2 hits). 16 edge-groups x 4 lanes (one float4
// each), 2x unrolled. p recomputed per slice (cheap); z precomputed.
__global__ __launch_bounds__(256) void gat_slice(
    const int* __restrict__ rowptr, const u16* __restrict__ csrc,
    const float* __restrict__ s_src, const float* __restrict__ s_dst,
    const float* __restrict__ zbuf, const float* __restrict__ h,
    const float* __restrict__ bias, float* __restrict__ xnext,
    int col_off, int slice) {
    int node = blockIdx.x * 4 + (threadIdx.x >> 6);
    if (node >= N_NODES) return;
    int lane = threadIdx.x & 63;
    int grp = lane >> 2;   // 0..15
    int sub = lane & 3;    // 0..3
    int base = slice * 4 + sub;   // float4 index within the 16-float4 row

    int beg = rowptr[node], end = rowptr[node + 1];
    float sd = s_dst[node];
    const float4* h4 = (const float4*)h;
    float4 acc = make_float4(0.f, 0.f, 0.f, 0.f);

    int k = beg + grp;
    for (; k + 16 < end; k += 32) {
        int s0 = csrc[k];
        int s1 = csrc[k + 16];
        float e0 = s_src[s0] + sd;
        float e1 = s_src[s1] + sd;
        e0 = (e0 >= 0.f) ? e0 : NEG_SLOPE * e0;
        e1 = (e1 >= 0.f) ? e1 : NEG_SLOPE * e1;
        float p0 = __expf(e0);
        float p1 = __expf(e1);
        float4 u = h4[(size_t)s0 * 16 + base];
        float4 v = h4[(size_t)s1 * 16 + base];
        acc.x += p0 * u.x + p1 * v.x; acc.y += p0 * u.y + p1 * v.y;
        acc.z += p0 * u.z + p1 * v.z; acc.w += p0 * u.w + p1 * v.w;
    }
    if (k < end) {
        int s0 = csrc[k];
        float e0 = s_src[s0] + sd;
        e0 = (e0 >= 0.f) ? e0 : NEG_SLOPE * e0;
        float p0 = __expf(e0);
        float4 u = h4[(size_t)s0 * 16 + base];
        acc.x += p0 * u.x; acc.y += p0 * u.y; acc.z += p0 * u.z; acc.w += p0 * u.w;
    }
    if (grp == 0) {  // self-loop exactly once
        float e0 = s_src[node] + sd;
        e0 = (e0 >= 0.f) ? e0 : NEG_SLOPE * e0;
        float p0 = __expf(e0);
        float4 u = h4[(size_t)node * 16 + base];
        acc.x += p0 * u.x; acc.y += p0 * u.y; acc.z += p0 * u.z; acc.w += p0 * u.w;
    }
    // combine 16 edge-groups (butterfly over lane bits 2..5)
#pragma unroll
    for (int off = 4; off <= 32; off <<= 1) {
        acc.x += __shfl_xor(acc.x, off); acc.y += __shfl_xor(acc.y, off);
        acc.z += __shfl_xor(acc.z, off); acc.w += __shfl_xor(acc.w, off);
    }
    if (grp == 0) {
        float inv = 1.f / zbuf[node];
        float4 bv = ((const float4*)bias)[slice * 4 + sub];
        float4 o;
        o.x = fmaxf(acc.x * inv + bv.x, 0.f);
        o.y = fmaxf(acc.y * inv + bv.y, 0.f);
        o.z = fmaxf(acc.z * inv + bv.z, 0.f);
        o.w = fmaxf(acc.w * inv + bv.w, 0.f);
        float4* outp = (float4*)(xnext + (size_t)node * HID + col_off + slice * 16);
        outp[sub] = o;
    }
}

// global add pool
__global__ void pool(const float* __restrict__ x, const int* __restrict__ batch,
                     float* __restrict__ g) {
    int i = blockIdx.x * blockDim.x + threadIdx.x;
    if (i >= N_NODES * HID) return;
    int node = i >> 7;
    int j = i & 127;
    atomicAdd(g + (size_t)batch[node] * HID + j, x[i]);
}

__global__ void final_lin(const float* __restrict__ g, const float* __restrict__ fw,
                          const float* __restrict__ fb, float* __restrict__ y) {
    int b = blockIdx.x;
    int t = threadIdx.x;
    __shared__ float sm[HID];
    sm[t] = g[(size_t)b * HID + t] * fw[t];
    __syncthreads();
    for (int off = 64; off > 0; off >>= 1) {
        if (t < off) sm[t] += sm[t + off];
        __syncthreads();
    }
    if (t == 0) y[b] = sm[0] + fb[0];
}

extern "C" void kernel_launch(void* const* d_in, const int* in_sizes, int n_in,
                              void* d_out, int out_size, void* d_ws, size_t ws_size,
                              hipStream_t stream) {
    const float* x_in    = (const float*)d_in[0];
    const int*   ei      = (const int*)d_in[1];
    const int*   di      = (const int*)d_in[2];
    const int*   batch   = (const int*)d_in[3];
    const float* lin_w   = (const float*)d_in[4];
    const float* att_src = (const float*)d_in[5];
    const float* att_dst = (const float*)d_in[6];
    const float* bias    = (const float*)d_in[7];
    const float* fw      = (const float*)d_in[8];
    const float* fb      = (const float*)d_in[9];
    float* y = (float*)d_out;

    char* wsb = (char*)d_ws;
    size_t off = 0;
    auto alloc_b = [&](size_t bytes) { void* p = (void*)(wsb + off);
                                       off += (bytes + 15) & ~(size_t)15; return p; };

    float* xbuf0 = (float*)alloc_b((size_t)N_NODES * HID * 4);
    float* xbuf1 = (float*)alloc_b((size_t)N_NODES * HID * 4);  // doubles as pairs
    float* h     = (float*)alloc_b((size_t)N_NODES * OUT_D * 4);
    float* s_src = (float*)alloc_b(N_NODES * 4);
    float* s_dst = (float*)alloc_b(N_NODES * 4);
    float* zbuf  = (float*)alloc_b(N_NODES * 4);
    float* g     = (float*)alloc_b((size_t)N_GRAPHS * HID * 4);
    int* mat     = (int*)alloc_b((size_t)NBUCK * NTILE * 4);
    int* matx    = (int*)alloc_b(((size_t)NBUCK * NTILE + 1) * 4);
    int* bsum    = (int*)alloc_b(64 * 4);
    int* bsumx   = (int*)alloc_b(64 * 4);
    int* rowS    = (int*)alloc_b((N_NODES + 1) * 4);
    int* rowD    = (int*)alloc_b((N_NODES + 1) * 4);
    u16* csrcS   = (u16*)alloc_b((size_t)E_SPARSE * 2);
    u16* csrcD   = (u16*)alloc_b((size_t)E_DENSE * 2);
    u32* pairs   = (u32*)xbuf1;  // 12.8 MB needed <= 25.6 MB available

    const int MATN = NBUCK * NTILE;                 // 100096
    const int SCAN_BLKS = (MATN + 2047) / 2048;     // 49 <= 64

    struct Br { const int* src; const int* dst; int E; int* row; u16* csrc; };
    Br brs[2] = {{di, di + E_DENSE, E_DENSE, rowD, csrcD},
                 {ei, ei + E_SPARSE, E_SPARSE, rowS, csrcS}};
    for (int b = 0; b < 2; ++b) {
        int TS = (brs[b].E + NTILE - 1) / NTILE;
        tile_count<<<NTILE, 256, 0, stream>>>(brs[b].dst, brs[b].E, TS, mat);
        scan_lvl0<<<SCAN_BLKS, 512, 0, stream>>>(mat, MATN, matx, bsum);
        scan_lvl1<<<1, 64, 0, stream>>>(bsum, SCAN_BLKS, bsumx);
        scan_add<<<(MATN + 256) / 256, 256, 0, stream>>>(matx, MATN, bsumx, brs[b].E);
        tile_scatter<<<NTILE, 256, 0, stream>>>(brs[b].src, brs[b].dst, brs[b].E, TS,
                                                matx, pairs);
        bucket_to_csr<<<NBUCK, 256, 0, stream>>>(pairs, matx, brs[b].E,
                                                 brs[b].row, brs[b].csrc);
    }

    // layer 0 reads x_in directly; outputs ping-pong xbuf1 -> xbuf0 -> xbuf1
    const float* cur = x_in;
    float* bufs[3] = {xbuf1, xbuf0, xbuf1};
    const int ngrid = (N_NODES + 3) / 4;
    for (int l = 0; l < N_LAYERS; ++l) {
        node_mm<<<N_NODES, 64, 0, stream>>>(cur, lin_w + (size_t)l * HID * OUT_D,
                                            att_src + l * OUT_D, att_dst + l * OUT_D,
                                            h, s_src, s_dst);
        float* xn = bufs[l];
        // sparse branch: fused single pass
        gat_aggr<<<ngrid, 256, 0, stream>>>(rowS, csrcS, s_src, s_dst, h,
                                            bias + l * OUT_D, xn, 0);
        // dense branch: z pass + 4 L2-resident dim-slice passes
        gat_z<<<ngrid, 256, 0, stream>>>(rowD, csrcD, s_src, s_dst, zbuf);
        for (int s = 0; s < 4; ++s)
            gat_slice<<<ngrid, 256, 0, stream>>>(rowD, csrcD, s_src, s_dst, zbuf, h,
                                                 bias + l * OUT_D, xn, OUT_D, s);
        cur = xn;
    }

    hipMemsetAsync(g, 0, sizeof(float) * (size_t)N_GRAPHS * HID, stream);
    pool<<<(N_NODES * HID + 255) / 256, 256, 0, stream>>>(cur, batch, g);
    final_lin<<<N_GRAPHS, HID, 0, stream>>>(g, fw, fb, y);
}

// Round 7
// 647.709 us; speedup vs baseline: 1.5937x; 1.5937x over previous
//
#include <hip/hip_runtime.h>

#define N_NODES 50000
#define N_GRAPHS 500
#define E_SPARSE 800000
#define E_DENSE 3200000
#define IN_DIM 128
#define HID 128
#define OUT_D 64
#define N_LAYERS 3
#define NEG_SLOPE 0.2f

#define BUCKET_SHIFT 7                 // 128 nodes per bucket
#define BUCKET_N 128
#define NBUCK 391                      // ceil(50000/128)
#define NTILE 256                      // edge tiles
#define NT 32                          // nodes per node_mm block
typedef unsigned int u32;
typedef unsigned short u16;

// ---------------- CSR construction (no global atomics) ---------------------

__global__ __launch_bounds__(256) void tile_count(const int* __restrict__ dst, int E,
                                                  int TS, int* __restrict__ mat) {
    __shared__ int hc[NBUCK];
    int t = threadIdx.x, tile = blockIdx.x;
    for (int i = t; i < NBUCK; i += 256) hc[i] = 0;
    __syncthreads();
    int beg = tile * TS, end = min(E, beg + TS);
    for (int i = beg + t; i < end; i += 256) atomicAdd(&hc[dst[i] >> BUCKET_SHIFT], 1);
    __syncthreads();
    for (int i = t; i < NBUCK; i += 256) mat[i * NTILE + tile] = hc[i];
}

__global__ void scan_lvl0(const int* __restrict__ cnt, int n,
                          int* __restrict__ out, int* __restrict__ bsum) {
    __shared__ int sm[512];
    int t = threadIdx.x;
    int base = blockIdx.x * 2048 + t * 4;
    int v0 = (base + 0 < n) ? cnt[base + 0] : 0;
    int v1 = (base + 1 < n) ? cnt[base + 1] : 0;
    int v2 = (base + 2 < n) ? cnt[base + 2] : 0;
    int v3 = (base + 3 < n) ? cnt[base + 3] : 0;
    int s = v0 + v1 + v2 + v3;
    sm[t] = s;
    __syncthreads();
    for (int off = 1; off < 512; off <<= 1) {
        int a = (t >= off) ? sm[t - off] : 0;
        __syncthreads();
        sm[t] += a;
        __syncthreads();
    }
    int excl = sm[t] - s;
    if (base + 0 < n) out[base + 0] = excl;
    if (base + 1 < n) out[base + 1] = excl + v0;
    if (base + 2 < n) out[base + 2] = excl + v0 + v1;
    if (base + 3 < n) out[base + 3] = excl + v0 + v1 + v2;
    if (t == 511) bsum[blockIdx.x] = sm[511];
}

__global__ void scan_lvl1(int* __restrict__ bsum, int nb, int* __restrict__ bsumx) {
    int t = threadIdx.x;
    int v = (t < nb) ? bsum[t] : 0;
    int orig = v;
    for (int off = 1; off < 64; off <<= 1) {
        int u = __shfl_up(v, off);
        if (t >= off) v += u;
    }
    if (t < nb) bsumx[t] = v - orig;
}

__global__ void scan_add(int* __restrict__ out, int n, const int* __restrict__ bsumx,
                         int Etot) {
    int i = blockIdx.x * blockDim.x + threadIdx.x;
    if (i < n) out[i] += bsumx[i >> 11];
    if (i == 0) out[n] = Etot;
}

__global__ __launch_bounds__(256) void tile_scatter(const int* __restrict__ src,
                                                    const int* __restrict__ dst, int E,
                                                    int TS, const int* __restrict__ matx,
                                                    u32* __restrict__ pairs) {
    __shared__ int cur[NBUCK];
    int t = threadIdx.x, tile = blockIdx.x;
    for (int i = t; i < NBUCK; i += 256) cur[i] = matx[i * NTILE + tile];
    __syncthreads();
    int beg = tile * TS, end = min(E, beg + TS);
    for (int i = beg + t; i < end; i += 256) {
        int d = dst[i];
        int pos = atomicAdd(&cur[d >> BUCKET_SHIFT], 1);
        pairs[pos] = (u32)src[i] | ((u32)(d & (BUCKET_N - 1)) << 16);
    }
}

__global__ __launch_bounds__(256) void bucket_to_csr(const u32* __restrict__ pairs,
                                                     const int* __restrict__ matx, int E,
                                                     int* __restrict__ rowptr,
                                                     u16* __restrict__ csrc) {
    int b = blockIdx.x;
    int t = threadIdx.x;
    int beg = matx[b * NTILE];
    int end = matx[(b + 1) * NTILE];
    __shared__ int lcnt[BUCKET_N];
    __shared__ int lofs[BUCKET_N];
    if (t < BUCKET_N) lcnt[t] = 0;
    __syncthreads();
    for (int k = beg + t; k < end; k += 256)
        atomicAdd(&lcnt[(pairs[k] >> 16) & (BUCKET_N - 1)], 1);
    __syncthreads();
    if (t < BUCKET_N) lofs[t] = lcnt[t];
    __syncthreads();
    for (int off = 1; off < BUCKET_N; off <<= 1) {
        int a = (t < BUCKET_N && t >= off) ? lofs[t - off] : 0;
        __syncthreads();
        if (t < BUCKET_N) lofs[t] += a;
        __syncthreads();
    }
    int node = (b << BUCKET_SHIFT) + t;
    if (t < BUCKET_N) {
        int excl = lofs[t] - lcnt[t];
        if (node < N_NODES) rowptr[node] = beg + excl;
        lcnt[t] = excl;  // reuse as cursor
    }
    if (b == NBUCK - 1 && t == 0) rowptr[N_NODES] = E;
    __syncthreads();
    for (int k = beg + t; k < end; k += 256) {
        u32 pr = pairs[k];
        int dl = (pr >> 16) & (BUCKET_N - 1);
        int pos = atomicAdd(&lcnt[dl], 1);
        csrc[beg + pos] = (u16)(pr & 0xffffu);
    }
}

// ---------------- per-layer kernels ----------------------------------------

// 256 threads, 32 nodes/block. W (32KB) + X tile (16.9KB, padded) in LDS.
// Thread = 2 nodes x 4 cols register tile. Kills the per-block W re-read
// (was 1.6GB L2 traffic with one wave/node).
__global__ __launch_bounds__(256) void node_mm2(
    const float* __restrict__ x, const float* __restrict__ W,
    const float* __restrict__ a_s, const float* __restrict__ a_d,
    float* __restrict__ h, float* __restrict__ s_src, float* __restrict__ s_dst) {
    __shared__ float Wl[IN_DIM * OUT_D];        // [k][c], 32 KB
    __shared__ float4 Xl4[NT * 33];             // [n][33] float4 (132 floats padded)
    int t = threadIdx.x;
    int nbase = blockIdx.x * NT;

    const float4* W4 = (const float4*)W;
    float4* Wl4 = (float4*)Wl;
#pragma unroll
    for (int i = 0; i < 8; ++i) Wl4[t + 256 * i] = W4[t + 256 * i];  // 2048 float4

    int nrows = min(NT, N_NODES - nbase);
    const float4* X4 = (const float4*)(x + (size_t)nbase * IN_DIM);
    for (int i = t; i < nrows * 32; i += 256)
        Xl4[(i >> 5) * 33 + (i & 31)] = X4[i];
    __syncthreads();

    int wv = t >> 6, l = t & 63;
    int c4 = l & 15;                 // float4-column 0..15
    int np = l >> 4;                 // 0..3
    int n0 = wv * 8 + np * 2, n1 = n0 + 1;   // block-local node ids
    const float* Xl = (const float*)Xl4;
    const float4* Wr = (const float4*)Wl;

    float4 A0 = make_float4(0.f, 0.f, 0.f, 0.f);
    float4 A1 = make_float4(0.f, 0.f, 0.f, 0.f);
#pragma unroll 4
    for (int k = 0; k < IN_DIM; ++k) {
        float4 w4 = Wr[k * 16 + c4];
        float x0 = Xl[n0 * 132 + k];
        float x1 = Xl[n1 * 132 + k];
        A0.x += x0 * w4.x; A0.y += x0 * w4.y; A0.z += x0 * w4.z; A0.w += x0 * w4.w;
        A1.x += x1 * w4.x; A1.y += x1 * w4.y; A1.z += x1 * w4.z; A1.w += x1 * w4.w;
    }
    int gn0 = nbase + n0, gn1 = nbase + n1;
    if (gn0 < N_NODES) ((float4*)(h + (size_t)gn0 * OUT_D))[c4] = A0;
    if (gn1 < N_NODES) ((float4*)(h + (size_t)gn1 * OUT_D))[c4] = A1;

    float4 as4 = ((const float4*)a_s)[c4];
    float4 ad4 = ((const float4*)a_d)[c4];
    float ps0 = A0.x * as4.x + A0.y * as4.y + A0.z * as4.z + A0.w * as4.w;
    float pd0 = A0.x * ad4.x + A0.y * ad4.y + A0.z * ad4.z + A0.w * ad4.w;
    float ps1 = A1.x * as4.x + A1.y * as4.y + A1.z * as4.z + A1.w * as4.w;
    float pd1 = A1.x * ad4.x + A1.y * ad4.y + A1.z * ad4.z + A1.w * ad4.w;
#pragma unroll
    for (int off = 1; off < 16; off <<= 1) {
        ps0 += __shfl_xor(ps0, off); pd0 += __shfl_xor(pd0, off);
        ps1 += __shfl_xor(ps1, off); pd1 += __shfl_xor(pd1, off);
    }
    if (c4 == 0) {
        if (gn0 < N_NODES) { s_src[gn0] = ps0; s_dst[gn0] = pd0; }
        if (gn1 < N_NODES) { s_src[gn1] = ps1; s_dst[gn1] = pd1; }
    }
}

// Fused GAT aggregation for BOTH branches in one dispatch:
// blocks [0, ngrid) -> sparse (col 0..63), [ngrid, 2*ngrid) -> dense (col 64..127).
// One wave per dst node; 8 edge-groups x 8 lanes; 2x unrolled; u16 csrc.
__global__ __launch_bounds__(256) void gat_aggr2(
    const int* __restrict__ rowS, const u16* __restrict__ csrcS,
    const int* __restrict__ rowD, const u16* __restrict__ csrcD,
    const float* __restrict__ s_src, const float* __restrict__ s_dst,
    const float* __restrict__ h, const float* __restrict__ bias,
    float* __restrict__ xnext, int ngrid) {
    int bid = blockIdx.x;
    const int* rowptr;
    const u16* csrc;
    int col_off;
    if (bid < ngrid) { rowptr = rowS; csrc = csrcS; col_off = 0; }
    else { bid -= ngrid; rowptr = rowD; csrc = csrcD; col_off = OUT_D; }

    int node = bid * 4 + (threadIdx.x >> 6);
    if (node >= N_NODES) return;
    int lane = threadIdx.x & 63;
    int grp = lane >> 3;   // 0..7
    int sub = lane & 7;    // 0..7

    int beg = rowptr[node];
    int end = rowptr[node + 1];
    float sd = s_dst[node];

    const float4* h4 = (const float4*)h;
    float4 a0 = make_float4(0.f, 0.f, 0.f, 0.f);
    float4 a1 = make_float4(0.f, 0.f, 0.f, 0.f);
    float z = 0.f;

    int k = beg + grp;
    for (; k + 8 < end; k += 16) {
        int s0 = csrc[k];
        int s1 = csrc[k + 8];
        float e0 = s_src[s0] + sd;
        float e1 = s_src[s1] + sd;
        e0 = (e0 >= 0.f) ? e0 : NEG_SLOPE * e0;
        e1 = (e1 >= 0.f) ? e1 : NEG_SLOPE * e1;
        float p0 = __expf(e0);
        float p1 = __expf(e1);
        float4 u0 = h4[(size_t)s0 * 16 + sub];
        float4 u1 = h4[(size_t)s0 * 16 + sub + 8];
        float4 v0 = h4[(size_t)s1 * 16 + sub];
        float4 v1 = h4[(size_t)s1 * 16 + sub + 8];
        z += p0 + p1;
        a0.x += p0 * u0.x + p1 * v0.x; a0.y += p0 * u0.y + p1 * v0.y;
        a0.z += p0 * u0.z + p1 * v0.z; a0.w += p0 * u0.w + p1 * v0.w;
        a1.x += p0 * u1.x + p1 * v1.x; a1.y += p0 * u1.y + p1 * v1.y;
        a1.z += p0 * u1.z + p1 * v1.z; a1.w += p0 * u1.w + p1 * v1.w;
    }
    if (k < end) {
        int s0 = csrc[k];
        float e0 = s_src[s0] + sd;
        e0 = (e0 >= 0.f) ? e0 : NEG_SLOPE * e0;
        float p0 = __expf(e0);
        float4 u0 = h4[(size_t)s0 * 16 + sub];
        float4 u1 = h4[(size_t)s0 * 16 + sub + 8];
        z += p0;
        a0.x += p0 * u0.x; a0.y += p0 * u0.y; a0.z += p0 * u0.z; a0.w += p0 * u0.w;
        a1.x += p0 * u1.x; a1.y += p0 * u1.y; a1.z += p0 * u1.z; a1.w += p0 * u1.w;
    }
    if (grp == 0) {  // self-loop exactly once
        float e0 = s_src[node] + sd;
        e0 = (e0 >= 0.f) ? e0 : NEG_SLOPE * e0;
        float p0 = __expf(e0);
        float4 u0 = h4[(size_t)node * 16 + sub];
        float4 u1 = h4[(size_t)node * 16 + sub + 8];
        z += p0;
        a0.x += p0 * u0.x; a0.y += p0 * u0.y; a0.z += p0 * u0.z; a0.w += p0 * u0.w;
        a1.x += p0 * u1.x; a1.y += p0 * u1.y; a1.z += p0 * u1.z; a1.w += p0 * u1.w;
    }
#pragma unroll
    for (int off = 8; off <= 32; off <<= 1) {
        a0.x += __shfl_xor(a0.x, off); a0.y += __shfl_xor(a0.y, off);
        a0.z += __shfl_xor(a0.z, off); a0.w += __shfl_xor(a0.w, off);
        a1.x += __shfl_xor(a1.x, off); a1.y += __shfl_xor(a1.y, off);
        a1.z += __shfl_xor(a1.z, off); a1.w += __shfl_xor(a1.w, off);
        z += __shfl_xor(z, off);
    }
    if (grp == 0) {
        float inv = 1.f / z;
        const float4* b4 = (const float4*)bias;
        float4 b0 = b4[sub], b1 = b4[sub + 8];
        float4 o0, o1;
        o0.x = a0.x * inv + b0.x; o0.y = a0.y * inv + b0.y;
        o0.z = a0.z * inv + b0.z; o0.w = a0.w * inv + b0.w;
        o1.x = a1.x * inv + b1.x; o1.y = a1.y * inv + b1.y;
        o1.z = a1.z * inv + b1.z; o1.w = a1.w * inv + b1.w;
        o0.x = fmaxf(o0.x, 0.f); o0.y = fmaxf(o0.y, 0.f);
        o0.z = fmaxf(o0.z, 0.f); o0.w = fmaxf(o0.w, 0.f);
        o1.x = fmaxf(o1.x, 0.f); o1.y = fmaxf(o1.y, 0.f);
        o1.z = fmaxf(o1.z, 0.f); o1.w = fmaxf(o1.w, 0.f);
        float4* outp = (float4*)(xnext + (size_t)node * HID + col_off);
        outp[sub] = o0;
        outp[sub + 8] = o1;
    }
}

// global add pool
__global__ void pool(const float* __restrict__ x, const int* __restrict__ batch,
                     float* __restrict__ g) {
    int i = blockIdx.x * blockDim.x + threadIdx.x;
    if (i >= N_NODES * HID) return;
    int node = i >> 7;
    int j = i & 127;
    atomicAdd(g + (size_t)batch[node] * HID + j, x[i]);
}

__global__ void final_lin(const float* __restrict__ g, const float* __restrict__ fw,
                          const float* __restrict__ fb, float* __restrict__ y) {
    int b = blockIdx.x;
    int t = threadIdx.x;
    __shared__ float sm[HID];
    sm[t] = g[(size_t)b * HID + t] * fw[t];
    __syncthreads();
    for (int off = 64; off > 0; off >>= 1) {
        if (t < off) sm[t] += sm[t + off];
        __syncthreads();
    }
    if (t == 0) y[b] = sm[0] + fb[0];
}

extern "C" void kernel_launch(void* const* d_in, const int* in_sizes, int n_in,
                              void* d_out, int out_size, void* d_ws, size_t ws_size,
                              hipStream_t stream) {
    const float* x_in    = (const float*)d_in[0];
    const int*   ei      = (const int*)d_in[1];
    const int*   di      = (const int*)d_in[2];
    const int*   batch   = (const int*)d_in[3];
    const float* lin_w   = (const float*)d_in[4];
    const float* att_src = (const float*)d_in[5];
    const float* att_dst = (const float*)d_in[6];
    const float* bias    = (const float*)d_in[7];
    const float* fw      = (const float*)d_in[8];
    const float* fb      = (const float*)d_in[9];
    float* y = (float*)d_out;

    char* wsb = (char*)d_ws;
    size_t off = 0;
    auto alloc_b = [&](size_t bytes) { void* p = (void*)(wsb + off);
                                       off += (bytes + 15) & ~(size_t)15; return p; };

    float* xbuf0 = (float*)alloc_b((size_t)N_NODES * HID * 4);
    float* xbuf1 = (float*)alloc_b((size_t)N_NODES * HID * 4);  // doubles as pairs
    float* h     = (float*)alloc_b((size_t)N_NODES * OUT_D * 4);
    float* s_src = (float*)alloc_b(N_NODES * 4);
    float* s_dst = (float*)alloc_b(N_NODES * 4);
    float* g     = (float*)alloc_b((size_t)N_GRAPHS * HID * 4);
    int* mat     = (int*)alloc_b((size_t)NBUCK * NTILE * 4);
    int* matx    = (int*)alloc_b(((size_t)NBUCK * NTILE + 1) * 4);
    int* bsum    = (int*)alloc_b(64 * 4);
    int* bsumx   = (int*)alloc_b(64 * 4);
    int* rowS    = (int*)alloc_b((N_NODES + 1) * 4);
    int* rowD    = (int*)alloc_b((N_NODES + 1) * 4);
    u16* csrcS   = (u16*)alloc_b((size_t)E_SPARSE * 2);
    u16* csrcD   = (u16*)alloc_b((size_t)E_DENSE * 2);
    u32* pairs   = (u32*)xbuf1;  // 12.8 MB needed <= 25.6 MB available

    const int MATN = NBUCK * NTILE;                 // 100096
    const int SCAN_BLKS = (MATN + 2047) / 2048;     // 49 <= 64

    struct Br { const int* src; const int* dst; int E; int* row; u16* csrc; };
    Br brs[2] = {{di, di + E_DENSE, E_DENSE, rowD, csrcD},
                 {ei, ei + E_SPARSE, E_SPARSE, rowS, csrcS}};
    for (int b = 0; b < 2; ++b) {
        int TS = (brs[b].E + NTILE - 1) / NTILE;
        tile_count<<<NTILE, 256, 0, stream>>>(brs[b].dst, brs[b].E, TS, mat);
        scan_lvl0<<<SCAN_BLKS, 512, 0, stream>>>(mat, MATN, matx, bsum);
        scan_lvl1<<<1, 64, 0, stream>>>(bsum, SCAN_BLKS, bsumx);
        scan_add<<<(MATN + 256) / 256, 256, 0, stream>>>(matx, MATN, bsumx, brs[b].E);
        tile_scatter<<<NTILE, 256, 0, stream>>>(brs[b].src, brs[b].dst, brs[b].E, TS,
                                                matx, pairs);
        bucket_to_csr<<<NBUCK, 256, 0, stream>>>(pairs, matx, brs[b].E,
                                                 brs[b].row, brs[b].csrc);
    }

    // layer 0 reads x_in directly; outputs ping-pong xbuf1 -> xbuf0 -> xbuf1
    const float* cur = x_in;
    float* bufs[3] = {xbuf1, xbuf0, xbuf1};
    const int ngrid = (N_NODES + 3) / 4;
    const int mm_grid = (N_NODES + NT - 1) / NT;
    for (int l = 0; l < N_LAYERS; ++l) {
        node_mm2<<<mm_grid, 256, 0, stream>>>(cur, lin_w + (size_t)l * HID * OUT_D,
                                              att_src + l * OUT_D, att_dst + l * OUT_D,
                                              h, s_src, s_dst);
        float* xn = bufs[l];
        gat_aggr2<<<2 * ngrid, 256, 0, stream>>>(rowS, csrcS, rowD, csrcD,
                                                 s_src, s_dst, h,
                                                 bias + l * OUT_D, xn, ngrid);
        cur = xn;
    }

    hipMemsetAsync(g, 0, sizeof(float) * (size_t)N_GRAPHS * HID, stream);
    pool<<<(N_NODES * HID + 255) / 256, 256, 0, stream>>>(cur, batch, g);
    final_lin<<<N_GRAPHS, HID, 0, stream>>>(g, fw, fb, y);
}

// Round 8
// 638.763 us; speedup vs baseline: 1.6160x; 1.0140x over previous
//
#include <hip/hip_runtime.h>

#define N_NODES 50000
#define N_GRAPHS 500
#define E_SPARSE 800000
#define E_DENSE 3200000
#define IN_DIM 128
#define HID 128
#define OUT_D 64
#define N_LAYERS 3
#define NEG_SLOPE 0.2f

#define BUCKET_SHIFT 7                 // 128 nodes per bucket
#define BUCKET_N 128
#define NBUCK 391                      // ceil(50000/128)
#define NTD 1024                       // dense edge tiles
#define NTS 256                        // sparse edge tiles
#define TS_D 3125                      // E_DENSE / NTD
#define TS_S 3125                      // E_SPARSE / NTS
#define MD (NBUCK * NTD)               // dense matrix size = 400384
#define MATN (NBUCK * (NTD + NTS))     // 500480
#define NT 32                          // nodes per node_mm block
typedef unsigned int u32;
typedef unsigned short u16;

// ---------------- CSR construction (both branches in one pass) -------------
// Combined count matrix layout (bucket-major so scan gives contiguous bucket
// ranges): dense (b,t) -> b*NTD + t ; sparse (b,t) -> MD + b*NTS + t.

__global__ __launch_bounds__(256) void tile_count_all(
    const int* __restrict__ dstD, const int* __restrict__ dstS,
    int* __restrict__ mat) {
    __shared__ int hc[NBUCK];
    int t = threadIdx.x;
    int tile = blockIdx.x;
    for (int i = t; i < NBUCK; i += 256) hc[i] = 0;
    __syncthreads();
    if (tile < NTD) {
        int beg = tile * TS_D, end = min(E_DENSE, beg + TS_D);
        for (int i = beg + t; i < end; i += 256)
            atomicAdd(&hc[dstD[i] >> BUCKET_SHIFT], 1);
        __syncthreads();
        for (int i = t; i < NBUCK; i += 256) mat[i * NTD + tile] = hc[i];
    } else {
        int st = tile - NTD;
        int beg = st * TS_S, end = min(E_SPARSE, beg + TS_S);
        for (int i = beg + t; i < end; i += 256)
            atomicAdd(&hc[dstS[i] >> BUCKET_SHIFT], 1);
        __syncthreads();
        for (int i = t; i < NBUCK; i += 256) mat[MD + i * NTS + st] = hc[i];
    }
}

// scan level-0: 512 threads, 4 elems/thread => 2048/block
__global__ void scan_lvl0(const int* __restrict__ cnt, int n,
                          int* __restrict__ out, int* __restrict__ bsum) {
    __shared__ int sm[512];
    int t = threadIdx.x;
    int base = blockIdx.x * 2048 + t * 4;
    int v0 = (base + 0 < n) ? cnt[base + 0] : 0;
    int v1 = (base + 1 < n) ? cnt[base + 1] : 0;
    int v2 = (base + 2 < n) ? cnt[base + 2] : 0;
    int v3 = (base + 3 < n) ? cnt[base + 3] : 0;
    int s = v0 + v1 + v2 + v3;
    sm[t] = s;
    __syncthreads();
    for (int off = 1; off < 512; off <<= 1) {
        int a = (t >= off) ? sm[t - off] : 0;
        __syncthreads();
        sm[t] += a;
        __syncthreads();
    }
    int excl = sm[t] - s;
    if (base + 0 < n) out[base + 0] = excl;
    if (base + 1 < n) out[base + 1] = excl + v0;
    if (base + 2 < n) out[base + 2] = excl + v0 + v1;
    if (base + 3 < n) out[base + 3] = excl + v0 + v1 + v2;
    if (t == 511) bsum[blockIdx.x] = sm[511];
}

// level-1: 256-thread LDS scan of block sums (nb <= 256)
__global__ void scan_lvl1(const int* __restrict__ bsum, int nb,
                          int* __restrict__ bsumx) {
    __shared__ int sm[256];
    int t = threadIdx.x;
    int v = (t < nb) ? bsum[t] : 0;
    sm[t] = v;
    __syncthreads();
    for (int off = 1; off < 256; off <<= 1) {
        int a = (t >= off) ? sm[t - off] : 0;
        __syncthreads();
        sm[t] += a;
        __syncthreads();
    }
    if (t < nb) bsumx[t] = sm[t] - v;
}

__global__ void scan_add(int* __restrict__ out, int n, const int* __restrict__ bsumx,
                         int Etot) {
    int i = blockIdx.x * blockDim.x + threadIdx.x;
    if (i < n) out[i] += bsumx[i >> 11];
    if (i == 0) out[n] = Etot;
}

// scatter packed (dst_low7<<16 | src) into globally-unique (bucket,tile) runs
__global__ __launch_bounds__(256) void tile_scatter_all(
    const int* __restrict__ srcD, const int* __restrict__ dstD,
    const int* __restrict__ srcS, const int* __restrict__ dstS,
    const int* __restrict__ matx, u32* __restrict__ pairs) {
    __shared__ int cur[NBUCK];
    int t = threadIdx.x;
    int tile = blockIdx.x;
    const int* src;
    const int* dst;
    int beg, end;
    if (tile < NTD) {
        for (int i = t; i < NBUCK; i += 256) cur[i] = matx[i * NTD + tile];
        src = srcD; dst = dstD;
        beg = tile * TS_D; end = min(E_DENSE, beg + TS_D);
    } else {
        int st = tile - NTD;
        for (int i = t; i < NBUCK; i += 256) cur[i] = matx[MD + i * NTS + st];
        src = srcS; dst = dstS;
        beg = st * TS_S; end = min(E_SPARSE, beg + TS_S);
    }
    __syncthreads();
    for (int i = beg + t; i < end; i += 256) {
        int d = dst[i];
        int pos = atomicAdd(&cur[d >> BUCKET_SHIFT], 1);
        pairs[pos] = (u32)src[i] | ((u32)(d & (BUCKET_N - 1)) << 16);
    }
}

// per-bucket local sort -> rowptr + u16 csrc. blocks [0,NBUCK)=dense, rest sparse.
__global__ __launch_bounds__(256) void bucket_to_csr_all(
    const u32* __restrict__ pairs, const int* __restrict__ matx,
    int* __restrict__ rowD, u16* __restrict__ csrcD,
    int* __restrict__ rowS, u16* __restrict__ csrcS) {
    int bid = blockIdx.x;
    int t = threadIdx.x;
    int b, beg, end, base;
    int* rowptr;
    u16* csrc;
    if (bid < NBUCK) {
        b = bid;
        beg = matx[b * NTD];
        end = matx[(b + 1) * NTD];     // b=390 -> matx[MD] = E_DENSE
        base = 0; rowptr = rowD; csrc = csrcD;
    } else {
        b = bid - NBUCK;
        beg = matx[MD + b * NTS];
        end = matx[MD + (b + 1) * NTS];  // last -> matx[MATN] = E_D+E_S
        base = E_DENSE; rowptr = rowS; csrc = csrcS;
    }
    __shared__ int lcnt[BUCKET_N];
    __shared__ int lofs[BUCKET_N];
    if (t < BUCKET_N) lcnt[t] = 0;
    __syncthreads();
    for (int k = beg + t; k < end; k += 256)
        atomicAdd(&lcnt[(pairs[k] >> 16) & (BUCKET_N - 1)], 1);
    __syncthreads();
    if (t < BUCKET_N) lofs[t] = lcnt[t];
    __syncthreads();
    for (int off = 1; off < BUCKET_N; off <<= 1) {
        int a = (t < BUCKET_N && t >= off) ? lofs[t - off] : 0;
        __syncthreads();
        if (t < BUCKET_N) lofs[t] += a;
        __syncthreads();
    }
    int node = (b << BUCKET_SHIFT) + t;
    int lbeg = beg - base;  // local CSR offset
    if (t < BUCKET_N) {
        int excl = lofs[t] - lcnt[t];
        if (node < N_NODES) rowptr[node] = lbeg + excl;
        lcnt[t] = excl;  // reuse as cursor
    }
    if (b == NBUCK - 1 && t == 0)
        rowptr[N_NODES] = (base == 0) ? E_DENSE : E_SPARSE;
    __syncthreads();
    for (int k = beg + t; k < end; k += 256) {
        u32 pr = pairs[k];
        int dl = (pr >> 16) & (BUCKET_N - 1);
        int pos = atomicAdd(&lcnt[dl], 1);
        csrc[lbeg + pos] = (u16)(pr & 0xffffu);
    }
}

// ---------------- per-layer kernels ----------------------------------------

// 256 threads, 32 nodes/block. W (32KB) + X tile (16.9KB, padded) in LDS.
__global__ __launch_bounds__(256) void node_mm2(
    const float* __restrict__ x, const float* __restrict__ W,
    const float* __restrict__ a_s, const float* __restrict__ a_d,
    float* __restrict__ h, float* __restrict__ s_src, float* __restrict__ s_dst) {
    __shared__ float Wl[IN_DIM * OUT_D];        // [k][c], 32 KB
    __shared__ float4 Xl4[NT * 33];             // [n][33] float4 padded
    int t = threadIdx.x;
    int nbase = blockIdx.x * NT;

    const float4* W4 = (const float4*)W;
    float4* Wl4 = (float4*)Wl;
#pragma unroll
    for (int i = 0; i < 8; ++i) Wl4[t + 256 * i] = W4[t + 256 * i];

    int nrows = min(NT, N_NODES - nbase);
    const float4* X4 = (const float4*)(x + (size_t)nbase * IN_DIM);
    for (int i = t; i < nrows * 32; i += 256)
        Xl4[(i >> 5) * 33 + (i & 31)] = X4[i];
    __syncthreads();

    int wv = t >> 6, l = t & 63;
    int c4 = l & 15;
    int np = l >> 4;
    int n0 = wv * 8 + np * 2, n1 = n0 + 1;
    const float* Xl = (const float*)Xl4;
    const float4* Wr = (const float4*)Wl;

    float4 A0 = make_float4(0.f, 0.f, 0.f, 0.f);
    float4 A1 = make_float4(0.f, 0.f, 0.f, 0.f);
#pragma unroll 4
    for (int k = 0; k < IN_DIM; ++k) {
        float4 w4 = Wr[k * 16 + c4];
        float x0 = Xl[n0 * 132 + k];
        float x1 = Xl[n1 * 132 + k];
        A0.x += x0 * w4.x; A0.y += x0 * w4.y; A0.z += x0 * w4.z; A0.w += x0 * w4.w;
        A1.x += x1 * w4.x; A1.y += x1 * w4.y; A1.z += x1 * w4.z; A1.w += x1 * w4.w;
    }
    int gn0 = nbase + n0, gn1 = nbase + n1;
    if (gn0 < N_NODES) ((float4*)(h + (size_t)gn0 * OUT_D))[c4] = A0;
    if (gn1 < N_NODES) ((float4*)(h + (size_t)gn1 * OUT_D))[c4] = A1;

    float4 as4 = ((const float4*)a_s)[c4];
    float4 ad4 = ((const float4*)a_d)[c4];
    float ps0 = A0.x * as4.x + A0.y * as4.y + A0.z * as4.z + A0.w * as4.w;
    float pd0 = A0.x * ad4.x + A0.y * ad4.y + A0.z * ad4.z + A0.w * ad4.w;
    float ps1 = A1.x * as4.x + A1.y * as4.y + A1.z * as4.z + A1.w * as4.w;
    float pd1 = A1.x * ad4.x + A1.y * ad4.y + A1.z * ad4.z + A1.w * ad4.w;
#pragma unroll
    for (int off = 1; off < 16; off <<= 1) {
        ps0 += __shfl_xor(ps0, off); pd0 += __shfl_xor(pd0, off);
        ps1 += __shfl_xor(ps1, off); pd1 += __shfl_xor(pd1, off);
    }
    if (c4 == 0) {
        if (gn0 < N_NODES) { s_src[gn0] = ps0; s_dst[gn0] = pd0; }
        if (gn1 < N_NODES) { s_src[gn1] = ps1; s_dst[gn1] = pd1; }
    }
}

// Fused GAT aggregation, both branches, one wave/node, 8 groups x 8 lanes,
// 4x unrolled (4 independent gather chains per group).
__global__ __launch_bounds__(256) void gat_aggr2(
    const int* __restrict__ rowS, const u16* __restrict__ csrcS,
    const int* __restrict__ rowD, const u16* __restrict__ csrcD,
    const float* __restrict__ s_src, const float* __restrict__ s_dst,
    const float* __restrict__ h, const float* __restrict__ bias,
    float* __restrict__ xnext, int ngrid) {
    int bid = blockIdx.x;
    const int* rowptr;
    const u16* csrc;
    int col_off;
    if (bid < ngrid) { rowptr = rowS; csrc = csrcS; col_off = 0; }
    else { bid -= ngrid; rowptr = rowD; csrc = csrcD; col_off = OUT_D; }

    int node = bid * 4 + (threadIdx.x >> 6);
    if (node >= N_NODES) return;
    int lane = threadIdx.x & 63;
    int grp = lane >> 3;   // 0..7
    int sub = lane & 7;    // 0..7

    int beg = rowptr[node];
    int end = rowptr[node + 1];
    float sd = s_dst[node];

    const float4* h4 = (const float4*)h;
    float4 a0 = make_float4(0.f, 0.f, 0.f, 0.f);
    float4 a1 = make_float4(0.f, 0.f, 0.f, 0.f);
    float z = 0.f;

    int k = beg + grp;
    for (; k + 24 < end; k += 32) {
        int s0 = csrc[k], s1 = csrc[k + 8], s2 = csrc[k + 16], s3 = csrc[k + 24];
        float e0 = s_src[s0] + sd, e1 = s_src[s1] + sd;
        float e2 = s_src[s2] + sd, e3 = s_src[s3] + sd;
        e0 = (e0 >= 0.f) ? e0 : NEG_SLOPE * e0;
        e1 = (e1 >= 0.f) ? e1 : NEG_SLOPE * e1;
        e2 = (e2 >= 0.f) ? e2 : NEG_SLOPE * e2;
        e3 = (e3 >= 0.f) ? e3 : NEG_SLOPE * e3;
        float p0 = __expf(e0), p1 = __expf(e1), p2 = __expf(e2), p3 = __expf(e3);
        float4 u0 = h4[(size_t)s0 * 16 + sub];
        float4 u1 = h4[(size_t)s0 * 16 + sub + 8];
        float4 v0 = h4[(size_t)s1 * 16 + sub];
        float4 v1 = h4[(size_t)s1 * 16 + sub + 8];
        float4 w0 = h4[(size_t)s2 * 16 + sub];
        float4 w1 = h4[(size_t)s2 * 16 + sub + 8];
        float4 q0 = h4[(size_t)s3 * 16 + sub];
        float4 q1 = h4[(size_t)s3 * 16 + sub + 8];
        z += (p0 + p1) + (p2 + p3);
        a0.x += p0 * u0.x + p1 * v0.x + p2 * w0.x + p3 * q0.x;
        a0.y += p0 * u0.y + p1 * v0.y + p2 * w0.y + p3 * q0.y;
        a0.z += p0 * u0.z + p1 * v0.z + p2 * w0.z + p3 * q0.z;
        a0.w += p0 * u0.w + p1 * v0.w + p2 * w0.w + p3 * q0.w;
        a1.x += p0 * u1.x + p1 * v1.x + p2 * w1.x + p3 * q1.x;
        a1.y += p0 * u1.y + p1 * v1.y + p2 * w1.y + p3 * q1.y;
        a1.z += p0 * u1.z + p1 * v1.z + p2 * w1.z + p3 * q1.z;
        a1.w += p0 * u1.w + p1 * v1.w + p2 * w1.w + p3 * q1.w;
    }
    for (; k + 8 < end; k += 16) {
        int s0 = csrc[k], s1 = csrc[k + 8];
        float e0 = s_src[s0] + sd, e1 = s_src[s1] + sd;
        e0 = (e0 >= 0.f) ? e0 : NEG_SLOPE * e0;
        e1 = (e1 >= 0.f) ? e1 : NEG_SLOPE * e1;
        float p0 = __expf(e0), p1 = __expf(e1);
        float4 u0 = h4[(size_t)s0 * 16 + sub];
        float4 u1 = h4[(size_t)s0 * 16 + sub + 8];
        float4 v0 = h4[(size_t)s1 * 16 + sub];
        float4 v1 = h4[(size_t)s1 * 16 + sub + 8];
        z += p0 + p1;
        a0.x += p0 * u0.x + p1 * v0.x; a0.y += p0 * u0.y + p1 * v0.y;
        a0.z += p0 * u0.z + p1 * v0.z; a0.w += p0 * u0.w + p1 * v0.w;
        a1.x += p0 * u1.x + p1 * v1.x; a1.y += p0 * u1.y + p1 * v1.y;
        a1.z += p0 * u1.z + p1 * v1.z; a1.w += p0 * u1.w + p1 * v1.w;
    }
    if (k < end) {
        int s0 = csrc[k];
        float e0 = s_src[s0] + sd;
        e0 = (e0 >= 0.f) ? e0 : NEG_SLOPE * e0;
        float p0 = __expf(e0);
        float4 u0 = h4[(size_t)s0 * 16 + sub];
        float4 u1 = h4[(size_t)s0 * 16 + sub + 8];
        z += p0;
        a0.x += p0 * u0.x; a0.y += p0 * u0.y; a0.z += p0 * u0.z; a0.w += p0 * u0.w;
        a1.x += p0 * u1.x; a1.y += p0 * u1.y; a1.z += p0 * u1.z; a1.w += p0 * u1.w;
    }
    if (grp == 0) {  // self-loop exactly once
        float e0 = s_src[node] + sd;
        e0 = (e0 >= 0.f) ? e0 : NEG_SLOPE * e0;
        float p0 = __expf(e0);
        float4 u0 = h4[(size_t)node * 16 + sub];
        float4 u1 = h4[(size_t)node * 16 + sub + 8];
        z += p0;
        a0.x += p0 * u0.x; a0.y += p0 * u0.y; a0.z += p0 * u0.z; a0.w += p0 * u0.w;
        a1.x += p0 * u1.x; a1.y += p0 * u1.y; a1.z += p0 * u1.z; a1.w += p0 * u1.w;
    }
#pragma unroll
    for (int off = 8; off <= 32; off <<= 1) {
        a0.x += __shfl_xor(a0.x, off); a0.y += __shfl_xor(a0.y, off);
        a0.z += __shfl_xor(a0.z, off); a0.w += __shfl_xor(a0.w, off);
        a1.x += __shfl_xor(a1.x, off); a1.y += __shfl_xor(a1.y, off);
        a1.z += __shfl_xor(a1.z, off); a1.w += __shfl_xor(a1.w, off);
        z += __shfl_xor(z, off);
    }
    if (grp == 0) {
        float inv = 1.f / z;
        const float4* b4 = (const float4*)bias;
        float4 b0 = b4[sub], b1 = b4[sub + 8];
        float4 o0, o1;
        o0.x = a0.x * inv + b0.x; o0.y = a0.y * inv + b0.y;
        o0.z = a0.z * inv + b0.z; o0.w = a0.w * inv + b0.w;
        o1.x = a1.x * inv + b1.x; o1.y = a1.y * inv + b1.y;
        o1.z = a1.z * inv + b1.z; o1.w = a1.w * inv + b1.w;
        o0.x = fmaxf(o0.x, 0.f); o0.y = fmaxf(o0.y, 0.f);
        o0.z = fmaxf(o0.z, 0.f); o0.w = fmaxf(o0.w, 0.f);
        o1.x = fmaxf(o1.x, 0.f); o1.y = fmaxf(o1.y, 0.f);
        o1.z = fmaxf(o1.z, 0.f); o1.w = fmaxf(o1.w, 0.f);
        float4* outp = (float4*)(xnext + (size_t)node * HID + col_off);
        outp[sub] = o0;
        outp[sub + 8] = o1;
    }
}

// Fused global_add_pool + final linear: one block per graph (batch is sorted).
__global__ __launch_bounds__(128) void pool_final(
    const float* __restrict__ x, const int* __restrict__ batch,
    const float* __restrict__ fw, const float* __restrict__ fb,
    float* __restrict__ y) {
    int b = blockIdx.x;
    int t = threadIdx.x;  // 0..127
    __shared__ int sbeg, send;
    if (t == 0) {
        int lo = 0, hi = N_NODES;
        while (lo < hi) { int mid = (lo + hi) >> 1; if (batch[mid] < b) lo = mid + 1; else hi = mid; }
        sbeg = lo;
        hi = N_NODES;
        while (lo < hi) { int mid = (lo + hi) >> 1; if (batch[mid] < b + 1) lo = mid + 1; else hi = mid; }
        send = lo;
    }
    __syncthreads();
    float acc = 0.f;
    for (int n = sbeg; n < send; ++n) acc += x[(size_t)n * HID + t];
    __shared__ float sm[HID];
    sm[t] = acc * fw[t];
    __syncthreads();
    for (int off = 64; off > 0; off >>= 1) {
        if (t < off) sm[t] += sm[t + off];
        __syncthreads();
    }
    if (t == 0) y[b] = sm[0] + fb[0];
}

extern "C" void kernel_launch(void* const* d_in, const int* in_sizes, int n_in,
                              void* d_out, int out_size, void* d_ws, size_t ws_size,
                              hipStream_t stream) {
    const float* x_in    = (const float*)d_in[0];
    const int*   ei      = (const int*)d_in[1];
    const int*   di      = (const int*)d_in[2];
    const int*   batch   = (const int*)d_in[3];
    const float* lin_w   = (const float*)d_in[4];
    const float* att_src = (const float*)d_in[5];
    const float* att_dst = (const float*)d_in[6];
    const float* bias    = (const float*)d_in[7];
    const float* fw      = (const float*)d_in[8];
    const float* fb      = (const float*)d_in[9];
    float* y = (float*)d_out;

    char* wsb = (char*)d_ws;
    size_t off = 0;
    auto alloc_b = [&](size_t bytes) { void* p = (void*)(wsb + off);
                                       off += (bytes + 15) & ~(size_t)15; return p; };

    float* xbuf0 = (float*)alloc_b((size_t)N_NODES * HID * 4);
    float* xbuf1 = (float*)alloc_b((size_t)N_NODES * HID * 4);  // pairs during build
    float* h     = (float*)alloc_b((size_t)N_NODES * OUT_D * 4);
    float* s_src = (float*)alloc_b(N_NODES * 4);
    float* s_dst = (float*)alloc_b(N_NODES * 4);
    int* mat     = (int*)alloc_b((size_t)MATN * 4);
    int* matx    = (int*)alloc_b(((size_t)MATN + 1) * 4);
    int* bsum    = (int*)alloc_b(256 * 4);
    int* bsumx   = (int*)alloc_b(256 * 4);
    int* rowS    = (int*)alloc_b((N_NODES + 1) * 4);
    int* rowD    = (int*)alloc_b((N_NODES + 1) * 4);
    u16* csrcS   = (u16*)alloc_b((size_t)E_SPARSE * 2);
    u16* csrcD   = (u16*)alloc_b((size_t)E_DENSE * 2);
    u32* pairs   = (u32*)xbuf1;  // 16 MB needed <= 25.6 MB available

    const int* srcD = di;
    const int* dstD = di + E_DENSE;
    const int* srcS = ei;
    const int* dstS = ei + E_SPARSE;

    const int SCAN_BLKS = (MATN + 2047) / 2048;  // 245 <= 256

    // ---- combined CSR build (5 launches, shared across layers) ----
    tile_count_all<<<NTD + NTS, 256, 0, stream>>>(dstD, dstS, mat);
    scan_lvl0<<<SCAN_BLKS, 512, 0, stream>>>(mat, MATN, matx, bsum);
    scan_lvl1<<<1, 256, 0, stream>>>(bsum, SCAN_BLKS, bsumx);
    scan_add<<<(MATN + 256) / 256, 256, 0, stream>>>(matx, MATN, bsumx,
                                                     E_DENSE + E_SPARSE);
    tile_scatter_all<<<NTD + NTS, 256, 0, stream>>>(srcD, dstD, srcS, dstS,
                                                    matx, pairs);
    bucket_to_csr_all<<<2 * NBUCK, 256, 0, stream>>>(pairs, matx, rowD, csrcD,
                                                     rowS, csrcS);

    // layer 0 reads x_in directly; outputs ping-pong xbuf1 -> xbuf0 -> xbuf1
    const float* cur = x_in;
    float* bufs[3] = {xbuf1, xbuf0, xbuf1};
    const int ngrid = (N_NODES + 3) / 4;
    const int mm_grid = (N_NODES + NT - 1) / NT;
    for (int l = 0; l < N_LAYERS; ++l) {
        node_mm2<<<mm_grid, 256, 0, stream>>>(cur, lin_w + (size_t)l * HID * OUT_D,
                                              att_src + l * OUT_D, att_dst + l * OUT_D,
                                              h, s_src, s_dst);
        float* xn = bufs[l];
        gat_aggr2<<<2 * ngrid, 256, 0, stream>>>(rowS, csrcS, rowD, csrcD,
                                                 s_src, s_dst, h,
                                                 bias + l * OUT_D, xn, ngrid);
        cur = xn;
    }

    pool_final<<<N_GRAPHS, 128, 0, stream>>>(cur, batch, fw, fb, y);
}